// Round 10
// baseline (202.385 us; speedup 1.0000x reference)
//
#include <hip/hip_runtime.h>
#include <stdint.h>

// Problem constants
#define B_ 4
#define S_ 2048
#define D_ 1024
#define H_ 16
#define DK_ 64
#define M_ (B_*S_)   // 8192 rows

typedef __attribute__((ext_vector_type(8))) short bhalf8;   // 8 x bf16 (4 VGPRs)
typedef __attribute__((ext_vector_type(4))) short bhalf4;   // 4 x bf16 (2 VGPRs)
typedef __attribute__((ext_vector_type(4))) float floatx4;  // MFMA accumulator
typedef unsigned short bfu;
typedef unsigned int u32;

// fp32 -> bf16 (RNE), branchless
__device__ __forceinline__ bfu f2bf(float f) {
  union { float f; u32 u; } v; v.f = f;
  u32 r = v.u + 0x7FFFu + ((v.u >> 16) & 1u);
  return (bfu)(r >> 16);
}

// packed fp32x2 -> bf16x2 via HW cvt (RNE); lo16 = a, hi16 = b
__device__ __forceinline__ u32 cvtpk(float a, float b) {
  u32 r;
  asm("v_cvt_pk_bf16_f32 %0, %1, %2" : "=v"(r) : "v"(a), "v"(b));
  return r;
}

// async global->LDS, 16B per lane; LDS dest = wave-uniform base + lane*16
__device__ __forceinline__ void gll16(const bfu* g, bfu* l) {
  __builtin_amdgcn_global_load_lds((__attribute__((address_space(1))) void*)g,
                                   (__attribute__((address_space(3))) void*)l,
                                   16, 0, 0);
}

// ---------------- fused conversion kernel: x + 4 weights -> contiguous bf16 ws ----------------
__global__ void cvt_all(const float* __restrict__ x,  const float* __restrict__ wq,
                        const float* __restrict__ wk, const float* __restrict__ wv,
                        const float* __restrict__ wo, bfu* __restrict__ dst) {
  const size_t u = ((size_t)blockIdx.x * blockDim.x + threadIdx.x) * 4;
  const size_t XN = (size_t)M_ * D_;           // 8.4M elems, block-aligned boundary
  const float* src;
  if (u < XN) {
    src = x + u;
  } else {
    const size_t v = u - XN;
    const int wsel = (int)(v >> 20);           // D_*D_ = 2^20
    const size_t off = v & ((size_t)(1u << 20) - 1);
    src = ((wsel == 0) ? wq : (wsel == 1) ? wk : (wsel == 2) ? wv : wo) + off;
  }
  float4 vv = *(const float4*)src;
  ushort4 o;
  o.x = f2bf(vv.x); o.y = f2bf(vv.y); o.z = f2bf(vv.z); o.w = f2bf(vv.w);
  *(ushort4*)(dst + u) = o;
}

// ---------------- GEMM core, ring-pipelined (T3+T4): C[128x128] = A * B^T ----------------
// 256 thr = 4 waves (2x2). BK=64, K=1024 -> 16 K-steps. LDS = 4-buffer ring of 32KB K-step
// tiles (A 16KB + B 16KB), 128KB total, 1 block/CU. STAGE(t+3) issued at top of step t
// (8x global_load_lds, pre-swizzled source cols, linear dest); end-of-step counted
// s_waitcnt vmcnt(16) (tile t+1 landed, t+2/t+3 stay in flight) + raw s_barrier.
// sched_barrier(0) pins the step's ds_reads/MFMAs before the wait (rule-18 insurance).
// Overwrite-safety: STAGE(t+3) targets buf[(t-1)&3], fully read before the prior barrier.
__device__ __forceinline__ void gemm_core_ring(const bfu* __restrict__ A,
                                               const bfu* __restrict__ Bw,
                                               bfu* smem,
                                               int m0, int bn0,
                                               floatx4 (&acc)[4][4])
{
  const int tid  = threadIdx.x;
  const int lane = tid & 63;
  const int g    = lane >> 4;
  const int i16  = lane & 15;
  const int w    = tid >> 6;
  const int wm   = w >> 1, wn = w & 1;

  const int lrow = lane >> 3;                       // 0..7
  const int scol = ((lane & 7) ^ lrow) << 3;        // pre-swizzled element col
  const bfu* As = A  + (size_t)(m0  + w * 32 + lrow) * D_ + scol;
  const bfu* Bs = Bw + (size_t)(bn0 + w * 32 + lrow) * D_ + scol;
  const int ldst = w * 4 * 512;                     // wave's LDS staging base (elems)

  auto STAGE = [&](int t) {
    bfu* base = smem + (t & 3) * 16384;
    const int k0 = t * 64;
#pragma unroll
    for (int j = 0; j < 4; ++j)
      gll16(As + (size_t)j * 8 * D_ + k0, base + ldst + j * 512);
#pragma unroll
    for (int j = 0; j < 4; ++j)
      gll16(Bs + (size_t)j * 8 * D_ + k0, base + 8192 + ldst + j * 512);
  };

  auto COMPUTE = [&](int t) {
    const char* aTc = (const char*)(smem + (t & 3) * 16384);
    const char* bTc = aTc + 16384;
    __builtin_amdgcn_s_setprio(1);
#pragma unroll
    for (int kb = 0; kb < 2; ++kb) {
      bhalf8 af[4], bf[4];
#pragma unroll
      for (int f = 0; f < 4; ++f) {
        int arow = wm * 64 + f * 16 + i16;
        af[f] = *(const bhalf8*)(aTc + arow * 128 + ((kb * 64 + g * 16) ^ ((arow & 7) << 4)));
        int brow = wn * 64 + f * 16 + i16;
        bf[f] = *(const bhalf8*)(bTc + brow * 128 + ((kb * 64 + g * 16) ^ ((brow & 7) << 4)));
      }
#pragma unroll
      for (int fm = 0; fm < 4; ++fm)
#pragma unroll
        for (int fn = 0; fn < 4; ++fn)
          acc[fm][fn] = __builtin_amdgcn_mfma_f32_16x16x32_bf16(af[fm], bf[fn], acc[fm][fn], 0, 0, 0);
    }
    __builtin_amdgcn_s_setprio(0);
  };

  // prologue: 3 K-tiles in flight, wait for tile 0 (oldest 8 of 24)
  STAGE(0); STAGE(1); STAGE(2);
  asm volatile("s_waitcnt vmcnt(16)" ::: "memory");
  __builtin_amdgcn_s_barrier();
  // steady state: t = 0..12 (stage t+3 <= 15)
  for (int t = 0; t < 13; ++t) {
    STAGE(t + 3);
    COMPUTE(t);
    __builtin_amdgcn_sched_barrier(0);
    asm volatile("s_waitcnt vmcnt(16)" ::: "memory");   // tile t+1 landed
    __builtin_amdgcn_s_barrier();
  }
  // drain: vmcnt 8 -> 0
  COMPUTE(13);
  __builtin_amdgcn_sched_barrier(0);
  asm volatile("s_waitcnt vmcnt(8)" ::: "memory");      // tile 14 landed
  __builtin_amdgcn_s_barrier();
  COMPUTE(14);
  __builtin_amdgcn_sched_barrier(0);
  asm volatile("s_waitcnt vmcnt(0)" ::: "memory");      // tile 15 landed
  __builtin_amdgcn_s_barrier();
  COMPUTE(15);
}

// ---------------- fused QKV projection GEMM: C[8192 x 3072] ----------------
__global__ __launch_bounds__(256) void qkv_gemm(const bfu* __restrict__ xb,
                                                const bfu* __restrict__ wqkv,
                                                bfu* __restrict__ Qd,
                                                bfu* __restrict__ Kd,
                                                bfu* __restrict__ Vtd)
{
  __shared__ bfu smem[4 * 16384];                 // 128KB ring
  const int bid = blockIdx.x;
  const int wi   = bid >> 3;
  const int xblk = wi >> 3;                       // 0..23
  const int y    = ((bid & 7) << 3) | (wi & 7);   // 0..63
  const int m0   = y * 128;
  const int z    = xblk >> 3;                     // 0:Q 1:K 2:V
  const int n0   = (xblk & 7) * 128;
  const int bn0  = xblk * 128;

  floatx4 acc[4][4] = {};
  gemm_core_ring(xb, wqkv, smem, m0, bn0, acc);

  bfu* dst = (z == 0) ? Qd : (z == 1) ? Kd : Vtd;
  const int lane = threadIdx.x & 63;
  const int g = lane >> 4, i16 = lane & 15;
  const int w = threadIdx.x >> 6, wm = w >> 1, wn = w & 1;
#pragma unroll
  for (int fm = 0; fm < 4; ++fm) {
#pragma unroll
    for (int fn = 0; fn < 4; ++fn) {
      int col = n0 + wn * 64 + fn * 16 + i16;
      int h = col >> 6, dk = col & 63;
#pragma unroll
      for (int r = 0; r < 4; ++r) {
        int mrow = m0 + wm * 64 + fm * 16 + g * 4 + r;
        int b = mrow >> 11, s = mrow & (S_ - 1);
        size_t idx = (z == 2)
            ? ((size_t)((b * H_ + h) * DK_ + dk)) * S_ + s    // V^T
            : ((size_t)((b * H_ + h) * S_ + s)) * DK_ + dk;   // Q,K
        dst[idx] = f2bf(acc[fm][fn][r]);
      }
    }
  }
}

// ---------------- output projection GEMM (fp32 out): C[8192 x 1024] ----------------
__global__ __launch_bounds__(256) void out_gemm(const bfu* __restrict__ Ab,
                                                const bfu* __restrict__ wob,
                                                float* __restrict__ out)
{
  __shared__ bfu smem[4 * 16384];                 // 128KB ring
  const int bid = blockIdx.x;
  const int wi   = bid >> 3;
  const int xblk = wi >> 3;                       // 0..7
  const int y    = ((bid & 7) << 3) | (wi & 7);
  const int m0   = y * 128;
  const int n0   = xblk * 128;

  floatx4 acc[4][4] = {};
  gemm_core_ring(Ab, wob, smem, m0, n0, acc);

  const int lane = threadIdx.x & 63;
  const int g = lane >> 4, i16 = lane & 15;
  const int w = threadIdx.x >> 6, wm = w >> 1, wn = w & 1;
#pragma unroll
  for (int fm = 0; fm < 4; ++fm)
#pragma unroll
    for (int fn = 0; fn < 4; ++fn) {
      int col = n0 + wn * 64 + fn * 16 + i16;
#pragma unroll
      for (int r = 0; r < 4; ++r) {
        int mrow = m0 + wm * 64 + fm * 16 + g * 4 + r;
        out[(size_t)mrow * D_ + col] = acc[fm][fn][r];
      }
    }
}

// ---------------- flash attention (causal): 8 waves, QBLK=128, paired q-blocks ----------------
// (unchanged from round 9)
template<int BUF>
__device__ __forceinline__ void attn_tile(const char* smem, int t, int ntw, int qr,
                                          int koff0, int koff1, const int (&voff)[4],
                                          bhalf8 qa0, bhalf8 qa1, int g, int i16,
                                          floatx4 (&ot)[4], float& mC2, float& lp)
{
  const float C2 = 0.125f * 1.44269504f;   // dk^-0.5 * log2(e)
  floatx4 sa[4] = {};
#pragma unroll
  for (int cb = 0; cb < 4; ++cb) {
    bhalf8 kf0 = *(const bhalf8*)(smem + BUF + cb * 2048 + koff0);
    bhalf8 kf1 = *(const bhalf8*)(smem + BUF + cb * 2048 + koff1);
    sa[cb] = __builtin_amdgcn_mfma_f32_16x16x32_bf16(kf0, qa0, sa[cb], 0, 0, 0);
    sa[cb] = __builtin_amdgcn_mfma_f32_16x16x32_bf16(kf1, qa1, sa[cb], 0, 0, 0);
  }
  if (t == ntw - 1) {
    const int kv0 = t * 64;
#pragma unroll
    for (int cb = 0; cb < 4; ++cb)
#pragma unroll
      for (int r = 0; r < 4; ++r)
        if (kv0 + cb * 16 + g * 4 + r > qr + i16) sa[cb][r] = -3.0e38f;
  }
  float pm = sa[0][0];
#pragma unroll
  for (int cb = 0; cb < 4; ++cb)
#pragma unroll
    for (int r = 0; r < 4; ++r)
      pm = fmaxf(pm, sa[cb][r]);
  pm = fmaxf(pm, __shfl_xor(pm, 16));
  pm = fmaxf(pm, __shfl_xor(pm, 32));
  const float pmC2 = pm * C2;
  if (!__all(pmC2 - mC2 <= 8.0f)) {
    const float nmax = fmaxf(mC2, pmC2);
    const float al = exp2f(mC2 - nmax);
    mC2 = nmax;
    lp *= al;
#pragma unroll
    for (int da = 0; da < 4; ++da)
#pragma unroll
      for (int r = 0; r < 4; ++r)
        ot[da][r] *= al;
  }
  const float nm = -mC2;
  u32 pk[8];
  float ps = 0.f;
#pragma unroll
  for (int cb = 0; cb < 4; ++cb) {
    float p0 = exp2f(__builtin_fmaf(sa[cb][0], C2, nm));
    float p1 = exp2f(__builtin_fmaf(sa[cb][1], C2, nm));
    float p2 = exp2f(__builtin_fmaf(sa[cb][2], C2, nm));
    float p3 = exp2f(__builtin_fmaf(sa[cb][3], C2, nm));
    ps += (p0 + p1) + (p2 + p3);
    pk[cb * 2]     = cvtpk(p0, p1);
    pk[cb * 2 + 1] = cvtpk(p2, p3);
  }
  lp += ps;
#pragma unroll
  for (int da = 0; da < 4; ++da) {
#pragma unroll
    for (int cb = 0; cb < 4; ++cb) {
      bhalf4 vf = *(const bhalf4*)(smem + BUF + voff[cb] + da * 2048);
      union { u32 u[2]; bhalf4 h; } pu;
      pu.u[0] = pk[cb * 2]; pu.u[1] = pk[cb * 2 + 1];
      ot[da] = __builtin_amdgcn_mfma_f32_16x16x16bf16_1k(vf, pu.h, ot[da], 0, 0, 0);
    }
  }
}

__global__ __launch_bounds__(512, 4) void attn_kernel(const bfu* __restrict__ Q,
                                                      const bfu* __restrict__ Kc,
                                                      const bfu* __restrict__ Vt,
                                                      bfu* __restrict__ Oc)
{
  __shared__ char smem[2 * 16384];
  const int tid = threadIdx.x;
  const int lane = tid & 63;
  const int w = tid >> 6;              // 0..7
  const int g = lane >> 4, i16 = lane & 15;
  const int sw = (i16 & 7) << 4;
  const int bh = blockIdx.x;
  const int y0 = blockIdx.y;           // 0..7

  const bfu* Qb = Q  + (size_t)bh * S_ * DK_;
  const bfu* Kb = Kc + (size_t)bh * S_ * DK_;
  const bfu* Vb = Vt + (size_t)bh * DK_ * S_;
  const int b = bh >> 4, h = bh & 15;

  const int srow = tid >> 3;           // 0..63
  const int scolb = (tid & 7) * 16;
  const bfu* kgp = Kb + srow * DK_ + (scolb >> 1);
  const bfu* vgp = Vb + (size_t)srow * S_ + (scolb >> 1);
  char* kld = smem + srow * 128 + (scolb ^ ((srow & 7) << 4));
  const int vsw = ((srow & 7) << 4) | (srow & 8);
  char* vld0 = smem + 8192 + srow * 128 + ((scolb    ) ^ vsw);
  char* vld1 = smem + 8192 + srow * 128 + ((scolb + 8) ^ vsw);

  const int koff0 = i16 * 128 + ((g * 16) ^ sw);
  const int koff1 = i16 * 128 + ((64 + g * 16) ^ sw);
  const int vswr = sw | (i16 & 8);
  int voff[4];
#pragma unroll
  for (int cb = 0; cb < 4; ++cb)
    voff[cb] = 8192 + i16 * 128 + ((cb * 32 + g * 8) ^ vswr);

  for (int pass = 0; pass < 2; ++pass) {
    const int y = pass ? (15 - y0) : y0;
    const int ntw = 2 * y + 1 + (w >> 2);
    const int qr = y * 128 + w * 16;
    const int spine = 2 * y + 2;       // even

    bhalf8 qa0 = *(const bhalf8*)(Qb + (size_t)(qr + i16) * DK_ + g * 8);
    bhalf8 qa1 = *(const bhalf8*)(Qb + (size_t)(qr + i16) * DK_ + 32 + g * 8);

    floatx4 ot[4] = {};
    float mC2 = -1.0e30f;
    float lp  = 0.f;

    union { bhalf8 h8; bhalf4 h4[2]; } vu;
    bhalf8 kst = *(const bhalf8*)kgp;
    bhalf8 vst = *(const bhalf8*)vgp;
    *(bhalf8*)kld = kst;
    vu.h8 = vst;
    *(bhalf4*)vld0 = vu.h4[0]; *(bhalf4*)vld1 = vu.h4[1];
    __syncthreads();

    const int half = spine >> 1;
    for (int i = 0; ; ++i) {
      const int t0 = 2 * i, t1 = 2 * i + 1;
      const bool more = (i + 1 < half);
      kst = *(const bhalf8*)(kgp + (size_t)t1 * 4096);
      vst = *(const bhalf8*)(vgp + t1 * 64);
      if (t0 < ntw)
        attn_tile<0>(smem, t0, ntw, qr, koff0, koff1, voff, qa0, qa1, g, i16, ot, mC2, lp);
      *(bhalf8*)(kld + 16384) = kst;
      vu.h8 = vst;
      *(bhalf4*)(vld0 + 16384) = vu.h4[0]; *(bhalf4*)(vld1 + 16384) = vu.h4[1];
      __syncthreads();
      if (more) {
        kst = *(const bhalf8*)(kgp + (size_t)(t0 + 2) * 4096);
        vst = *(const bhalf8*)(vgp + (t0 + 2) * 64);
      }
      if (t1 < ntw)
        attn_tile<16384>(smem, t1, ntw, qr, koff0, koff1, voff, qa0, qa1, g, i16, ot, mC2, lp);
      if (!more) break;
      *(bhalf8*)kld = kst;
      vu.h8 = vst;
      *(bhalf4*)vld0 = vu.h4[0]; *(bhalf4*)vld1 = vu.h4[1];
      __syncthreads();
    }
    __syncthreads();   // all waves done with buffers before next pass reuses them

    float lt = lp;
    lt += __shfl_xor(lt, 16);
    lt += __shfl_xor(lt, 32);
    const float rl = 1.0f / lt;
    const size_t rowbase = (size_t)(b * S_ + qr + i16) * D_ + h * 64;
#pragma unroll
    for (int da = 0; da < 4; ++da) {
      union { u32 u[2]; uint2 v; } ov;
      ov.u[0] = cvtpk(ot[da][0] * rl, ot[da][1] * rl);
      ov.u[1] = cvtpk(ot[da][2] * rl, ot[da][3] * rl);
      *(uint2*)(Oc + rowbase + da * 16 + g * 4) = ov.v;
    }
  }
}

// ---------------- launch ----------------
extern "C" void kernel_launch(void* const* d_in, const int* in_sizes, int n_in,
                              void* d_out, int out_size, void* d_ws, size_t ws_size,
                              hipStream_t stream)
{
  const float* x  = (const float*)d_in[0];
  const float* wq = (const float*)d_in[1];
  const float* wk = (const float*)d_in[2];
  const float* wv = (const float*)d_in[3];
  const float* wo = (const float*)d_in[4];

  bfu* xb  = (bfu*)d_ws;                          // [8192][1024]
  bfu* wqb = xb  + (size_t)M_ * D_;               // [3072][1024] = W_qkv contiguous
  bfu* wob = wqb + (size_t)3 * D_ * D_;           // [1024][1024]
  bfu* Qd  = wob + (size_t)D_ * D_;               // [bh][s][dk]
  bfu* Kd  = Qd  + (size_t)M_ * D_;               // [bh][s][dk]
  bfu* Vtd = Kd  + (size_t)M_ * D_;               // [bh][dk][s]
  bfu* Ad  = Vtd + (size_t)M_ * D_;               // attn out bf16 [b][s][d]

  const size_t total = (size_t)M_ * D_ + 4 * (size_t)D_ * D_;   // 12582912
  cvt_all<<<(int)(total / 4 / 256), 256, 0, stream>>>(x, wq, wk, wv, wo, xb);

  qkv_gemm<<<1536, 256, 0, stream>>>(xb, wqb, Qd, Kd, Vtd);
  attn_kernel<<<dim3(B_ * H_, 8), 512, 0, stream>>>(Qd, Kd, Vtd, Ad);
  out_gemm<<<512, 256, 0, stream>>>(Ad, wob, (float*)d_out);
}

// Round 11
// 183.354 us; speedup vs baseline: 1.1038x; 1.1038x over previous
//
#include <hip/hip_runtime.h>
#include <stdint.h>

// Problem constants
#define B_ 4
#define S_ 2048
#define D_ 1024
#define H_ 16
#define DK_ 64
#define M_ (B_*S_)   // 8192 rows

typedef __attribute__((ext_vector_type(8))) short bhalf8;   // 8 x bf16 (4 VGPRs)
typedef __attribute__((ext_vector_type(4))) short bhalf4;   // 4 x bf16 (2 VGPRs)
typedef __attribute__((ext_vector_type(4))) float floatx4;  // MFMA accumulator
typedef unsigned short bfu;
typedef unsigned int u32;

// fp32 -> bf16 (RNE), branchless
__device__ __forceinline__ bfu f2bf(float f) {
  union { float f; u32 u; } v; v.f = f;
  u32 r = v.u + 0x7FFFu + ((v.u >> 16) & 1u);
  return (bfu)(r >> 16);
}

// packed fp32x2 -> bf16x2 via HW cvt (RNE); lo16 = a, hi16 = b
__device__ __forceinline__ u32 cvtpk(float a, float b) {
  u32 r;
  asm("v_cvt_pk_bf16_f32 %0, %1, %2" : "=v"(r) : "v"(a), "v"(b));
  return r;
}

// async global->LDS, 16B per lane; LDS dest = wave-uniform base + lane*16
__device__ __forceinline__ void gll16(const bfu* g, bfu* l) {
  __builtin_amdgcn_global_load_lds((__attribute__((address_space(1))) void*)g,
                                   (__attribute__((address_space(3))) void*)l,
                                   16, 0, 0);
}

// ---------------- fused conversion kernel: x + 4 weights -> contiguous bf16 ws ----------------
__global__ void cvt_all(const float* __restrict__ x,  const float* __restrict__ wq,
                        const float* __restrict__ wk, const float* __restrict__ wv,
                        const float* __restrict__ wo, bfu* __restrict__ dst) {
  const size_t u = ((size_t)blockIdx.x * blockDim.x + threadIdx.x) * 4;
  const size_t XN = (size_t)M_ * D_;           // 8.4M elems, block-aligned boundary
  const float* src;
  if (u < XN) {
    src = x + u;
  } else {
    const size_t v = u - XN;
    const int wsel = (int)(v >> 20);           // D_*D_ = 2^20
    const size_t off = v & ((size_t)(1u << 20) - 1);
    src = ((wsel == 0) ? wq : (wsel == 1) ? wk : (wsel == 2) ? wv : wo) + off;
  }
  float4 vv = *(const float4*)src;
  ushort4 o;
  o.x = f2bf(vv.x); o.y = f2bf(vv.y); o.z = f2bf(vv.z); o.w = f2bf(vv.w);
  *(ushort4*)(dst + u) = o;
}

// ---------------- GEMM core, 2-phase dbuf (T3-minimum): C[128x128] = A * B^T ----------------
// 256 thr = 4 waves (2x2). BK=64, 16 K-steps. LDS = 2 x 32KB K-step buffers (64KB,
// 2 blocks/CU). Per step: STAGE(t+1 -> buf^1) issued FIRST (8x global_load_lds,
// pre-swizzled source cols, linear dest), then COMPUTE(t from buf) (ds_read + 32 MFMA),
// then ONE __syncthreads() (its vmcnt(0)+lgkmcnt(0) drain is exactly the t+1-landed wait;
// load latency hides under COMPUTE). Overwrite safety: STAGE(t+1) targets the buffer
// read by COMPUTE(t-1), complete before the prior barrier.
__device__ __forceinline__ void gemm_core_2ph(const bfu* __restrict__ A,
                                              const bfu* __restrict__ Bw,
                                              bfu* smem,
                                              int m0, int bn0,
                                              floatx4 (&acc)[4][4])
{
  const int tid  = threadIdx.x;
  const int lane = tid & 63;
  const int g    = lane >> 4;
  const int i16  = lane & 15;
  const int w    = tid >> 6;
  const int wm   = w >> 1, wn = w & 1;

  const int lrow = lane >> 3;                       // 0..7
  const int scol = ((lane & 7) ^ lrow) << 3;        // pre-swizzled element col
  const bfu* As = A  + (size_t)(m0  + w * 32 + lrow) * D_ + scol;
  const bfu* Bs = Bw + (size_t)(bn0 + w * 32 + lrow) * D_ + scol;
  const int ldst = w * 4 * 512;                     // wave's LDS staging base (elems)

  auto STAGE = [&](int t) {
    bfu* base = smem + (t & 1) * 16384;
    const int k0 = t * 64;
#pragma unroll
    for (int j = 0; j < 4; ++j)
      gll16(As + (size_t)j * 8 * D_ + k0, base + ldst + j * 512);
#pragma unroll
    for (int j = 0; j < 4; ++j)
      gll16(Bs + (size_t)j * 8 * D_ + k0, base + 8192 + ldst + j * 512);
  };

  auto COMPUTE = [&](int t) {
    const char* aTc = (const char*)(smem + (t & 1) * 16384);
    const char* bTc = aTc + 16384;
    __builtin_amdgcn_s_setprio(1);
#pragma unroll
    for (int kb = 0; kb < 2; ++kb) {
      bhalf8 af[4], bf[4];
#pragma unroll
      for (int f = 0; f < 4; ++f) {
        int arow = wm * 64 + f * 16 + i16;
        af[f] = *(const bhalf8*)(aTc + arow * 128 + ((kb * 64 + g * 16) ^ ((arow & 7) << 4)));
        int brow = wn * 64 + f * 16 + i16;
        bf[f] = *(const bhalf8*)(bTc + brow * 128 + ((kb * 64 + g * 16) ^ ((brow & 7) << 4)));
      }
#pragma unroll
      for (int fm = 0; fm < 4; ++fm)
#pragma unroll
        for (int fn = 0; fn < 4; ++fn)
          acc[fm][fn] = __builtin_amdgcn_mfma_f32_16x16x32_bf16(af[fm], bf[fn], acc[fm][fn], 0, 0, 0);
    }
    __builtin_amdgcn_s_setprio(0);
  };

  STAGE(0);
  __syncthreads();                       // tile 0 landed
  for (int t = 0; t < 16; ++t) {
    if (t + 1 < 16) STAGE(t + 1);        // issue next-tile loads first (latency under COMPUTE)
    COMPUTE(t);
    __syncthreads();                     // drains vmcnt(0): tile t+1 landed; buffers safe
  }
}

// ---------------- fused QKV projection GEMM: C[8192 x 3072] ----------------
__global__ __launch_bounds__(256) void qkv_gemm(const bfu* __restrict__ xb,
                                                const bfu* __restrict__ wqkv,
                                                bfu* __restrict__ Qd,
                                                bfu* __restrict__ Kd,
                                                bfu* __restrict__ Vtd)
{
  __shared__ bfu smem[2 * 16384];                 // 64KB dbuf
  const int bid = blockIdx.x;
  const int wi   = bid >> 3;
  const int xblk = wi >> 3;                       // 0..23
  const int y    = ((bid & 7) << 3) | (wi & 7);   // 0..63
  const int m0   = y * 128;
  const int z    = xblk >> 3;                     // 0:Q 1:K 2:V
  const int n0   = (xblk & 7) * 128;
  const int bn0  = xblk * 128;

  floatx4 acc[4][4] = {};
  gemm_core_2ph(xb, wqkv, smem, m0, bn0, acc);

  bfu* dst = (z == 0) ? Qd : (z == 1) ? Kd : Vtd;
  const int lane = threadIdx.x & 63;
  const int g = lane >> 4, i16 = lane & 15;
  const int w = threadIdx.x >> 6, wm = w >> 1, wn = w & 1;
#pragma unroll
  for (int fm = 0; fm < 4; ++fm) {
#pragma unroll
    for (int fn = 0; fn < 4; ++fn) {
      int col = n0 + wn * 64 + fn * 16 + i16;
      int h = col >> 6, dk = col & 63;
#pragma unroll
      for (int r = 0; r < 4; ++r) {
        int mrow = m0 + wm * 64 + fm * 16 + g * 4 + r;
        int b = mrow >> 11, s = mrow & (S_ - 1);
        size_t idx = (z == 2)
            ? ((size_t)((b * H_ + h) * DK_ + dk)) * S_ + s    // V^T
            : ((size_t)((b * H_ + h) * S_ + s)) * DK_ + dk;   // Q,K
        dst[idx] = f2bf(acc[fm][fn][r]);
      }
    }
  }
}

// ---------------- output projection GEMM (fp32 out): C[8192 x 1024] ----------------
__global__ __launch_bounds__(256) void out_gemm(const bfu* __restrict__ Ab,
                                                const bfu* __restrict__ wob,
                                                float* __restrict__ out)
{
  __shared__ bfu smem[2 * 16384];                 // 64KB dbuf
  const int bid = blockIdx.x;
  const int wi   = bid >> 3;
  const int xblk = wi >> 3;                       // 0..7
  const int y    = ((bid & 7) << 3) | (wi & 7);
  const int m0   = y * 128;
  const int n0   = xblk * 128;

  floatx4 acc[4][4] = {};
  gemm_core_2ph(Ab, wob, smem, m0, n0, acc);

  const int lane = threadIdx.x & 63;
  const int g = lane >> 4, i16 = lane & 15;
  const int w = threadIdx.x >> 6, wm = w >> 1, wn = w & 1;
#pragma unroll
  for (int fm = 0; fm < 4; ++fm)
#pragma unroll
    for (int fn = 0; fn < 4; ++fn) {
      int col = n0 + wn * 64 + fn * 16 + i16;
#pragma unroll
      for (int r = 0; r < 4; ++r) {
        int mrow = m0 + wm * 64 + fm * 16 + g * 4 + r;
        out[(size_t)mrow * D_ + col] = acc[fm][fn][r];
      }
    }
}

// ---------------- flash attention (causal): 8 waves, QBLK=128, paired q-blocks ----------------
// (unchanged from round 9)
template<int BUF>
__device__ __forceinline__ void attn_tile(const char* smem, int t, int ntw, int qr,
                                          int koff0, int koff1, const int (&voff)[4],
                                          bhalf8 qa0, bhalf8 qa1, int g, int i16,
                                          floatx4 (&ot)[4], float& mC2, float& lp)
{
  const float C2 = 0.125f * 1.44269504f;   // dk^-0.5 * log2(e)
  floatx4 sa[4] = {};
#pragma unroll
  for (int cb = 0; cb < 4; ++cb) {
    bhalf8 kf0 = *(const bhalf8*)(smem + BUF + cb * 2048 + koff0);
    bhalf8 kf1 = *(const bhalf8*)(smem + BUF + cb * 2048 + koff1);
    sa[cb] = __builtin_amdgcn_mfma_f32_16x16x32_bf16(kf0, qa0, sa[cb], 0, 0, 0);
    sa[cb] = __builtin_amdgcn_mfma_f32_16x16x32_bf16(kf1, qa1, sa[cb], 0, 0, 0);
  }
  if (t == ntw - 1) {
    const int kv0 = t * 64;
#pragma unroll
    for (int cb = 0; cb < 4; ++cb)
#pragma unroll
      for (int r = 0; r < 4; ++r)
        if (kv0 + cb * 16 + g * 4 + r > qr + i16) sa[cb][r] = -3.0e38f;
  }
  float pm = sa[0][0];
#pragma unroll
  for (int cb = 0; cb < 4; ++cb)
#pragma unroll
    for (int r = 0; r < 4; ++r)
      pm = fmaxf(pm, sa[cb][r]);
  pm = fmaxf(pm, __shfl_xor(pm, 16));
  pm = fmaxf(pm, __shfl_xor(pm, 32));
  const float pmC2 = pm * C2;
  if (!__all(pmC2 - mC2 <= 8.0f)) {
    const float nmax = fmaxf(mC2, pmC2);
    const float al = exp2f(mC2 - nmax);
    mC2 = nmax;
    lp *= al;
#pragma unroll
    for (int da = 0; da < 4; ++da)
#pragma unroll
      for (int r = 0; r < 4; ++r)
        ot[da][r] *= al;
  }
  const float nm = -mC2;
  u32 pk[8];
  float ps = 0.f;
#pragma unroll
  for (int cb = 0; cb < 4; ++cb) {
    float p0 = exp2f(__builtin_fmaf(sa[cb][0], C2, nm));
    float p1 = exp2f(__builtin_fmaf(sa[cb][1], C2, nm));
    float p2 = exp2f(__builtin_fmaf(sa[cb][2], C2, nm));
    float p3 = exp2f(__builtin_fmaf(sa[cb][3], C2, nm));
    ps += (p0 + p1) + (p2 + p3);
    pk[cb * 2]     = cvtpk(p0, p1);
    pk[cb * 2 + 1] = cvtpk(p2, p3);
  }
  lp += ps;
#pragma unroll
  for (int da = 0; da < 4; ++da) {
#pragma unroll
    for (int cb = 0; cb < 4; ++cb) {
      bhalf4 vf = *(const bhalf4*)(smem + BUF + voff[cb] + da * 2048);
      union { u32 u[2]; bhalf4 h; } pu;
      pu.u[0] = pk[cb * 2]; pu.u[1] = pk[cb * 2 + 1];
      ot[da] = __builtin_amdgcn_mfma_f32_16x16x16bf16_1k(vf, pu.h, ot[da], 0, 0, 0);
    }
  }
}

__global__ __launch_bounds__(512, 4) void attn_kernel(const bfu* __restrict__ Q,
                                                      const bfu* __restrict__ Kc,
                                                      const bfu* __restrict__ Vt,
                                                      bfu* __restrict__ Oc)
{
  __shared__ char smem[2 * 16384];
  const int tid = threadIdx.x;
  const int lane = tid & 63;
  const int w = tid >> 6;              // 0..7
  const int g = lane >> 4, i16 = lane & 15;
  const int sw = (i16 & 7) << 4;
  const int bh = blockIdx.x;
  const int y0 = blockIdx.y;           // 0..7

  const bfu* Qb = Q  + (size_t)bh * S_ * DK_;
  const bfu* Kb = Kc + (size_t)bh * S_ * DK_;
  const bfu* Vb = Vt + (size_t)bh * DK_ * S_;
  const int b = bh >> 4, h = bh & 15;

  const int srow = tid >> 3;           // 0..63
  const int scolb = (tid & 7) * 16;
  const bfu* kgp = Kb + srow * DK_ + (scolb >> 1);
  const bfu* vgp = Vb + (size_t)srow * S_ + (scolb >> 1);
  char* kld = smem + srow * 128 + (scolb ^ ((srow & 7) << 4));
  const int vsw = ((srow & 7) << 4) | (srow & 8);
  char* vld0 = smem + 8192 + srow * 128 + ((scolb    ) ^ vsw);
  char* vld1 = smem + 8192 + srow * 128 + ((scolb + 8) ^ vsw);

  const int koff0 = i16 * 128 + ((g * 16) ^ sw);
  const int koff1 = i16 * 128 + ((64 + g * 16) ^ sw);
  const int vswr = sw | (i16 & 8);
  int voff[4];
#pragma unroll
  for (int cb = 0; cb < 4; ++cb)
    voff[cb] = 8192 + i16 * 128 + ((cb * 32 + g * 8) ^ vswr);

  for (int pass = 0; pass < 2; ++pass) {
    const int y = pass ? (15 - y0) : y0;
    const int ntw = 2 * y + 1 + (w >> 2);
    const int qr = y * 128 + w * 16;
    const int spine = 2 * y + 2;       // even

    bhalf8 qa0 = *(const bhalf8*)(Qb + (size_t)(qr + i16) * DK_ + g * 8);
    bhalf8 qa1 = *(const bhalf8*)(Qb + (size_t)(qr + i16) * DK_ + 32 + g * 8);

    floatx4 ot[4] = {};
    float mC2 = -1.0e30f;
    float lp  = 0.f;

    union { bhalf8 h8; bhalf4 h4[2]; } vu;
    bhalf8 kst = *(const bhalf8*)kgp;
    bhalf8 vst = *(const bhalf8*)vgp;
    *(bhalf8*)kld = kst;
    vu.h8 = vst;
    *(bhalf4*)vld0 = vu.h4[0]; *(bhalf4*)vld1 = vu.h4[1];
    __syncthreads();

    const int half = spine >> 1;
    for (int i = 0; ; ++i) {
      const int t0 = 2 * i, t1 = 2 * i + 1;
      const bool more = (i + 1 < half);
      kst = *(const bhalf8*)(kgp + (size_t)t1 * 4096);
      vst = *(const bhalf8*)(vgp + t1 * 64);
      if (t0 < ntw)
        attn_tile<0>(smem, t0, ntw, qr, koff0, koff1, voff, qa0, qa1, g, i16, ot, mC2, lp);
      *(bhalf8*)(kld + 16384) = kst;
      vu.h8 = vst;
      *(bhalf4*)(vld0 + 16384) = vu.h4[0]; *(bhalf4*)(vld1 + 16384) = vu.h4[1];
      __syncthreads();
      if (more) {
        kst = *(const bhalf8*)(kgp + (size_t)(t0 + 2) * 4096);
        vst = *(const bhalf8*)(vgp + (t0 + 2) * 64);
      }
      if (t1 < ntw)
        attn_tile<16384>(smem, t1, ntw, qr, koff0, koff1, voff, qa0, qa1, g, i16, ot, mC2, lp);
      if (!more) break;
      *(bhalf8*)kld = kst;
      vu.h8 = vst;
      *(bhalf4*)vld0 = vu.h4[0]; *(bhalf4*)vld1 = vu.h4[1];
      __syncthreads();
    }
    __syncthreads();   // all waves done with buffers before next pass reuses them

    float lt = lp;
    lt += __shfl_xor(lt, 16);
    lt += __shfl_xor(lt, 32);
    const float rl = 1.0f / lt;
    const size_t rowbase = (size_t)(b * S_ + qr + i16) * D_ + h * 64;
#pragma unroll
    for (int da = 0; da < 4; ++da) {
      union { u32 u[2]; uint2 v; } ov;
      ov.u[0] = cvtpk(ot[da][0] * rl, ot[da][1] * rl);
      ov.u[1] = cvtpk(ot[da][2] * rl, ot[da][3] * rl);
      *(uint2*)(Oc + rowbase + da * 16 + g * 4) = ov.v;
    }
  }
}

// ---------------- launch ----------------
extern "C" void kernel_launch(void* const* d_in, const int* in_sizes, int n_in,
                              void* d_out, int out_size, void* d_ws, size_t ws_size,
                              hipStream_t stream)
{
  const float* x  = (const float*)d_in[0];
  const float* wq = (const float*)d_in[1];
  const float* wk = (const float*)d_in[2];
  const float* wv = (const float*)d_in[3];
  const float* wo = (const float*)d_in[4];

  bfu* xb  = (bfu*)d_ws;                          // [8192][1024]
  bfu* wqb = xb  + (size_t)M_ * D_;               // [3072][1024] = W_qkv contiguous
  bfu* wob = wqb + (size_t)3 * D_ * D_;           // [1024][1024]
  bfu* Qd  = wob + (size_t)D_ * D_;               // [bh][s][dk]
  bfu* Kd  = Qd  + (size_t)M_ * D_;               // [bh][s][dk]
  bfu* Vtd = Kd  + (size_t)M_ * D_;               // [bh][dk][s]
  bfu* Ad  = Vtd + (size_t)M_ * D_;               // attn out bf16 [b][s][d]

  const size_t total = (size_t)M_ * D_ + 4 * (size_t)D_ * D_;   // 12582912
  cvt_all<<<(int)(total / 4 / 256), 256, 0, stream>>>(x, wq, wk, wv, wo, xb);

  qkv_gemm<<<1536, 256, 0, stream>>>(xb, wqb, Qd, Kd, Vtd);
  attn_kernel<<<dim3(B_ * H_, 8), 512, 0, stream>>>(Qd, Kd, Vtd, Ad);
  out_gemm<<<512, 256, 0, stream>>>(Ad, wob, (float*)d_out);
}